// Round 1
// baseline (6465.446 us; speedup 1.0000x reference)
//
#include <hip/hip_runtime.h>
#include <math.h>

#define L_ 2
#define B_ 2
#define C_ 256
#define H_ 8
#define HD_ 32
#define T_ 16
#define S_ 512
#define DFF_ 1024
#define NTS (T_*S_)                 // 8192
#define NELEM ((size_t)B_*C_*T_*S_) // 4194304

// ---------------- elementwise ----------------
__global__ void copy_kernel(const float* __restrict__ src, float* __restrict__ dst, int n4) {
    int i = blockIdx.x * blockDim.x + threadIdx.x;
    if (i < n4) ((float4*)dst)[i] = ((const float4*)src)[i];
}

__global__ void add_kernel(const float* __restrict__ a, const float* __restrict__ b,
                           float* __restrict__ o, int n4) {
    int i = blockIdx.x * blockDim.x + threadIdx.x;
    if (i < n4) {
        float4 x = ((const float4*)a)[i];
        float4 y = ((const float4*)b)[i];
        o[i*4+0] = x.x + y.x; o[i*4+1] = x.y + y.y;
        o[i*4+2] = x.z + y.z; o[i*4+3] = x.w + y.w;
    }
}

// ---------------- layernorm over channel dim ----------------
// x: [B,C,T,S]; one thread per (b,t,s) position, loop over C.
// optionally writes qk = src2 + pos
__global__ void ln_kernel(const float* __restrict__ x, const float* __restrict__ gamma,
                          const float* __restrict__ beta, const float* __restrict__ pos,
                          float* __restrict__ src2, float* __restrict__ qk) {
    int sblk = blockIdx.x % (S_/256);
    int t = (blockIdx.x / (S_/256)) % T_;
    int b = blockIdx.x / ((S_/256) * T_);
    int s = sblk * 256 + threadIdx.x;
    size_t base = ((size_t)b * C_ * T_ + t) * S_ + s;  // [b][0][t][s]; channel stride = NTS
    float sum = 0.f, sumsq = 0.f;
    for (int c = 0; c < C_; ++c) {
        float v = x[base + (size_t)c * NTS];
        sum += v; sumsq += v * v;
    }
    float mean = sum * (1.0f / C_);
    float var  = sumsq * (1.0f / C_) - mean * mean;
    float rstd = rsqrtf(var + 1e-5f);
    for (int c = 0; c < C_; ++c) {
        size_t idx = base + (size_t)c * NTS;
        float y = (x[idx] - mean) * rstd * gamma[c] + beta[c];
        src2[idx] = y;
        if (qk) qk[idx] = y + pos[idx];
    }
}

// ---------------- channel GEMM ----------------
// Y[b][m][n] (op)= sum_k W[m][k] * X[b][k][n] + bias[m]; N = NTS
// MODE 0: store, 1: accumulate (residual into Y), 2: relu+store
template<int MODE>
__global__ __launch_bounds__(256) void gemm_cc(const float* __restrict__ W,
                                               const float* __restrict__ bias,
                                               const float* __restrict__ X,
                                               float* __restrict__ Y, int M, int K) {
    __shared__ float Ws[16][64];
    __shared__ float Xs[16][64];
    int b  = blockIdx.z;
    int m0 = blockIdx.y * 64;
    int n0 = blockIdx.x * 64;
    const float* Xb = X + (size_t)b * K * NTS;
    float*       Yb = Y + (size_t)b * M * NTS;
    int tid = threadIdx.x;
    int tx = tid & 15, ty = tid >> 4;
    float acc[4][4] = {};
    for (int k0 = 0; k0 < K; k0 += 16) {
        #pragma unroll
        for (int i = 0; i < 4; ++i) {
            int idx = tid + 256 * i;
            int mm = idx >> 4, kk = idx & 15;
            Ws[kk][mm] = W[(size_t)(m0 + mm) * K + k0 + kk];
        }
        #pragma unroll
        for (int i = 0; i < 4; ++i) {
            int idx = tid + 256 * i;
            int kk = idx >> 6, nn = idx & 63;
            Xs[kk][nn] = Xb[(size_t)(k0 + kk) * NTS + n0 + nn];
        }
        __syncthreads();
        #pragma unroll
        for (int kk = 0; kk < 16; ++kk) {
            float a[4], bb[4];
            #pragma unroll
            for (int i = 0; i < 4; ++i) a[i] = Ws[kk][ty*4 + i];
            #pragma unroll
            for (int j = 0; j < 4; ++j) bb[j] = Xs[kk][tx*4 + j];
            #pragma unroll
            for (int i = 0; i < 4; ++i)
                #pragma unroll
                for (int j = 0; j < 4; ++j) acc[i][j] += a[i] * bb[j];
        }
        __syncthreads();
    }
    #pragma unroll
    for (int i = 0; i < 4; ++i) {
        int m = m0 + ty*4 + i;
        float bv = bias[m];
        #pragma unroll
        for (int j = 0; j < 4; ++j) {
            int n = n0 + tx*4 + j;
            size_t idx = (size_t)m * NTS + n;
            float val = acc[i][j] + bv;
            if (MODE == 2) val = fmaxf(val, 0.f);
            if (MODE == 1) Yb[idx] += val;
            else           Yb[idx] = val;
        }
    }
}

// ---------------- distance-gated attention ----------------
// q,k,v,out: [B,C,T,S] with c = h*HD + d. One wave per query row.
// grid = B*H*T*(S/4), block = 256 (4 waves)
__global__ __launch_bounds__(256) void attn_kernel(
        const float* __restrict__ q, const float* __restrict__ k,
        const float* __restrict__ v, const float* __restrict__ coord,
        const int* __restrict__ mask, float* __restrict__ out) {
    __shared__ float qv[4][HD_];
    __shared__ float probs[4][S_];
    int bid = blockIdx.x;
    int qg = bid & (S_/4 - 1);          // 7 bits
    int t  = (bid >> 7) & (T_ - 1);     // 4 bits
    int h  = (bid >> 11) & (H_ - 1);    // 3 bits
    int b  = bid >> 14;
    int wave = threadIdx.x >> 6;
    int lane = threadIdx.x & 63;
    int qi = qg * 4 + wave;
    size_t headbase = (((size_t)b * C_ + h * HD_) * T_ + t) * S_;  // [b][h*HD][t][0]
    if (lane < HD_) qv[wave][lane] = q[headbase + (size_t)lane * NTS + qi];
    __syncthreads();
    size_t cbase = (size_t)(b * T_ + t) * S_ * 3;
    float cq0 = coord[cbase + qi*3 + 0];
    float cq1 = coord[cbase + qi*3 + 1];
    float cq2 = coord[cbase + qi*3 + 2];
    const int* mrow = mask + (size_t)(b * T_ + t) * S_;
    float lg[8];
    #pragma unroll
    for (int j = 0; j < 8; ++j) {
        int kk = j * 64 + lane;
        float acc = 0.f;
        #pragma unroll
        for (int d = 0; d < HD_; ++d)
            acc += qv[wave][d] * k[headbase + (size_t)d * NTS + kk];
        acc *= 0.17677669529663687f;    // 1/sqrt(32)
        float dx = cq0 - coord[cbase + kk*3 + 0];
        float dy = cq1 - coord[cbase + kk*3 + 1];
        float dz = cq2 - coord[cbase + kk*3 + 2];
        float d2 = dx*dx + dy*dy + dz*dz;
        if (d2 >= 625.0f) acc = 0.f;          // gate: sqrt(d2) < 25
        if (mrow[kk] != 0) acc = -9e15f;      // key-padding mask
        lg[j] = acc;
    }
    // stable softmax over 512 keys (8 per lane x 64 lanes)
    float m = lg[0];
    #pragma unroll
    for (int j = 1; j < 8; ++j) m = fmaxf(m, lg[j]);
    for (int off = 32; off; off >>= 1) m = fmaxf(m, __shfl_xor(m, off, 64));
    float ssum = 0.f;
    #pragma unroll
    for (int j = 0; j < 8; ++j) { lg[j] = __expf(lg[j] - m); ssum += lg[j]; }
    for (int off = 32; off; off >>= 1) ssum += __shfl_xor(ssum, off, 64);
    float inv = 1.0f / ssum;
    #pragma unroll
    for (int j = 0; j < 8; ++j) probs[wave][j*64 + lane] = lg[j] * inv;
    __syncthreads();
    // attn @ V: 32 d-lanes x 2 key-halves
    int d = lane & 31, half = lane >> 5;
    const float* vrow = v + headbase + (size_t)d * NTS;
    int kb0 = half * 256;
    float acc = 0.f;
    for (int kk = 0; kk < 256; ++kk) acc += probs[wave][kb0 + kk] * vrow[kb0 + kk];
    acc += __shfl_xor(acc, 32, 64);
    if (half == 0) out[headbase + (size_t)d * NTS + qi] = acc;
}

// ---------------- driver ----------------
extern "C" void kernel_launch(void* const* d_in, const int* in_sizes, int n_in,
                              void* d_out, int out_size, void* d_ws, size_t ws_size,
                              hipStream_t stream) {
    const float* decoder = (const float*)d_in[0];
    const float* encoder = (const float*)d_in[1];
    const float* pos     = (const float*)d_in[2];
    const float* coord   = (const float*)d_in[3];
    const int*   mask    = (const int*)d_in[4];
    const float* Wq = (const float*)d_in[5],  *bq = (const float*)d_in[6];
    const float* Wk = (const float*)d_in[7],  *bk = (const float*)d_in[8];
    const float* Wv = (const float*)d_in[9],  *bv = (const float*)d_in[10];
    const float* Wo = (const float*)d_in[11], *bo = (const float*)d_in[12];
    const float* W1 = (const float*)d_in[13], *b1 = (const float*)d_in[14];
    const float* W2 = (const float*)d_in[15], *b2 = (const float*)d_in[16];
    const float* ln_g = (const float*)d_in[17], *ln_b = (const float*)d_in[18];

    float* dec = (float*)d_out;
    float* ws  = (float*)d_ws;
    // buffer plan (each NELEM floats): buf0=src2/vals, buf1=qk/v/h0, buf2=q/h1,
    // buf3=k/h2, buf4=h3  -> 5*16MiB = 84MB of d_ws
    float* buf0 = ws;
    float* buf1 = ws + NELEM;
    float* buf2 = ws + 2*NELEM;
    float* buf3 = ws + 3*NELEM;
    float* hbuf = buf1;                 // spans buf1..buf4 (4*NELEM = B*DFF*T*S)

    int n4 = (int)(NELEM / 4);
    dim3 ewGrid(n4 / 256);
    dim3 gemmGridC(NTS/64, C_/64, B_);
    dim3 gemmGridF(NTS/64, DFF_/64, B_);
    dim3 lnGrid(B_ * T_ * (S_/256));
    dim3 attnGrid(B_ * H_ * T_ * (S_/4));

    copy_kernel<<<ewGrid, 256, 0, stream>>>(decoder, dec, n4);

    for (int l = 0; l < L_; ++l) {
        const float* Wq_l = Wq + (size_t)l*C_*C_;  const float* bq_l = bq + l*C_;
        const float* Wk_l = Wk + (size_t)l*C_*C_;  const float* bk_l = bk + l*C_;
        const float* Wv_l = Wv + (size_t)l*C_*C_;  const float* bv_l = bv + l*C_;
        const float* Wo_l = Wo + (size_t)l*C_*C_;  const float* bo_l = bo + l*C_;
        const float* W1_l = W1 + (size_t)l*DFF_*C_; const float* b1_l = b1 + l*DFF_;
        const float* W2_l = W2 + (size_t)l*C_*DFF_; const float* b2_l = b2 + l*C_;
        const float* g0 = ln_g + ((size_t)l*3 + 0)*C_; const float* e0 = ln_b + ((size_t)l*3 + 0)*C_;
        const float* g1 = ln_g + ((size_t)l*3 + 1)*C_; const float* e1 = ln_b + ((size_t)l*3 + 1)*C_;
        const float* g2 = ln_g + ((size_t)l*3 + 2)*C_; const float* e2 = ln_b + ((size_t)l*3 + 2)*C_;

        // ---- block A: self-attention, qk = LN(dec)+pos, v-input = LN(dec)
        ln_kernel<<<lnGrid, 256, 0, stream>>>(dec, g0, e0, pos, buf0, buf1);
        gemm_cc<0><<<gemmGridC, 256, 0, stream>>>(Wq_l, bq_l, buf1, buf2, C_, C_);
        gemm_cc<0><<<gemmGridC, 256, 0, stream>>>(Wk_l, bk_l, buf1, buf3, C_, C_);
        gemm_cc<0><<<gemmGridC, 256, 0, stream>>>(Wv_l, bv_l, buf0, buf1, C_, C_);
        attn_kernel<<<attnGrid, 256, 0, stream>>>(buf2, buf3, buf1, coord, mask, buf0);
        gemm_cc<1><<<gemmGridC, 256, 0, stream>>>(Wo_l, bo_l, buf0, dec, C_, C_);

        // ---- block B: qk = encoder+pos, v-input = LN(dec)
        ln_kernel<<<lnGrid, 256, 0, stream>>>(dec, g1, e1, nullptr, buf0, nullptr);
        add_kernel<<<ewGrid, 256, 0, stream>>>(encoder, pos, buf1, n4);
        gemm_cc<0><<<gemmGridC, 256, 0, stream>>>(Wq_l, bq_l, buf1, buf2, C_, C_);
        gemm_cc<0><<<gemmGridC, 256, 0, stream>>>(Wk_l, bk_l, buf1, buf3, C_, C_);
        gemm_cc<0><<<gemmGridC, 256, 0, stream>>>(Wv_l, bv_l, buf0, buf1, C_, C_);
        attn_kernel<<<attnGrid, 256, 0, stream>>>(buf2, buf3, buf1, coord, mask, buf0);
        gemm_cc<1><<<gemmGridC, 256, 0, stream>>>(Wo_l, bo_l, buf0, dec, C_, C_);

        // ---- FFN
        ln_kernel<<<lnGrid, 256, 0, stream>>>(dec, g2, e2, nullptr, buf0, nullptr);
        gemm_cc<2><<<gemmGridF, 256, 0, stream>>>(W1_l, b1_l, buf0, hbuf, DFF_, C_);
        gemm_cc<1><<<gemmGridC, 256, 0, stream>>>(W2_l, b2_l, hbuf, dec, C_, DFF_);
    }
}

// Round 2
// 2767.909 us; speedup vs baseline: 2.3359x; 2.3359x over previous
//
#include <hip/hip_runtime.h>
#include <hip/hip_fp16.h>
#include <math.h>

#define L_ 2
#define B_ 2
#define C_ 256
#define H_ 8
#define HD_ 32
#define T_ 16
#define S_ 512
#define DFF_ 1024
#define NTS (T_*S_)                 // 8192
#define NELEM ((size_t)B_*C_*T_*S_) // 4194304

typedef __attribute__((ext_vector_type(8))) _Float16 half8;

// ---------------- elementwise ----------------
__global__ void copy_kernel(const float* __restrict__ src, float* __restrict__ dst, int n4) {
    int i = blockIdx.x * blockDim.x + threadIdx.x;
    if (i < n4) ((float4*)dst)[i] = ((const float4*)src)[i];
}

__global__ void add_kernel(const float* __restrict__ a, const float* __restrict__ b,
                           float* __restrict__ o, int n4) {
    int i = blockIdx.x * blockDim.x + threadIdx.x;
    if (i < n4) {
        float4 x = ((const float4*)a)[i];
        float4 y = ((const float4*)b)[i];
        float4 r; r.x = x.x + y.x; r.y = x.y + y.y; r.z = x.z + y.z; r.w = x.w + y.w;
        ((float4*)o)[i] = r;
    }
}

// ---------------- layernorm over channel dim ----------------
__global__ void ln_kernel(const float* __restrict__ x, const float* __restrict__ gamma,
                          const float* __restrict__ beta, const float* __restrict__ pos,
                          float* __restrict__ src2, float* __restrict__ qk) {
    int sblk = blockIdx.x % (S_/256);
    int t = (blockIdx.x / (S_/256)) % T_;
    int b = blockIdx.x / ((S_/256) * T_);
    int s = sblk * 256 + threadIdx.x;
    size_t base = ((size_t)b * C_ * T_ + t) * S_ + s;
    float sum = 0.f, sumsq = 0.f;
    for (int c = 0; c < C_; ++c) {
        float v = x[base + (size_t)c * NTS];
        sum += v; sumsq += v * v;
    }
    float mean = sum * (1.0f / C_);
    float var  = sumsq * (1.0f / C_) - mean * mean;
    float rstd = rsqrtf(var + 1e-5f);
    for (int c = 0; c < C_; ++c) {
        size_t idx = base + (size_t)c * NTS;
        float y = (x[idx] - mean) * rstd * gamma[c] + beta[c];
        src2[idx] = y;
        if (qk) qk[idx] = y + pos[idx];
    }
}

// ---------------- channel GEMM ----------------
// Y[b][m][n] (op)= sum_k W[m][k] * X[b][k][n] + bias[m]; N = NTS
// MODE 0: store, 1: accumulate (residual), 2: relu+store
template<int MODE>
__global__ __launch_bounds__(256) void gemm_cc(const float* __restrict__ W,
                                               const float* __restrict__ bias,
                                               const float* __restrict__ X,
                                               float* __restrict__ Y, int M, int K) {
    __shared__ float Ws[16][64];
    __shared__ float Xs[16][64];
    int b  = blockIdx.z;
    int m0 = blockIdx.y * 64;
    int n0 = blockIdx.x * 64;
    const float* Xb = X + (size_t)b * K * NTS;
    float*       Yb = Y + (size_t)b * M * NTS;
    int tid = threadIdx.x;
    int tx = tid & 15, ty = tid >> 4;
    float acc[4][4] = {};
    for (int k0 = 0; k0 < K; k0 += 16) {
        #pragma unroll
        for (int i = 0; i < 4; ++i) {
            int idx = tid + 256 * i;
            int mm = idx >> 4, kk = idx & 15;
            Ws[kk][mm] = W[(size_t)(m0 + mm) * K + k0 + kk];
        }
        #pragma unroll
        for (int i = 0; i < 4; ++i) {
            int idx = tid + 256 * i;
            int kk = idx >> 6, nn = idx & 63;
            Xs[kk][nn] = Xb[(size_t)(k0 + kk) * NTS + n0 + nn];
        }
        __syncthreads();
        #pragma unroll
        for (int kk = 0; kk < 16; ++kk) {
            float a[4], bb[4];
            #pragma unroll
            for (int i = 0; i < 4; ++i) a[i] = Ws[kk][ty*4 + i];
            #pragma unroll
            for (int j = 0; j < 4; ++j) bb[j] = Xs[kk][tx*4 + j];
            #pragma unroll
            for (int i = 0; i < 4; ++i)
                #pragma unroll
                for (int j = 0; j < 4; ++j) acc[i][j] += a[i] * bb[j];
        }
        __syncthreads();
    }
    #pragma unroll
    for (int i = 0; i < 4; ++i) {
        int m = m0 + ty*4 + i;
        float bv = bias[m];
        #pragma unroll
        for (int j = 0; j < 4; ++j) {
            int n = n0 + tx*4 + j;
            size_t idx = (size_t)m * NTS + n;
            float val = acc[i][j] + bv;
            if (MODE == 2) val = fmaxf(val, 0.f);
            if (MODE == 1) Yb[idx] += val;
            else           Yb[idx] = val;
        }
    }
}

// ---------------- gate/mask bit precompute ----------------
// One wave per query row. gw bit = near && unmasked (use exp(s));
// fw bit = far && unmasked (use exp(0)=1); neither -> masked (0).
__global__ __launch_bounds__(256) void gate_kernel(const float* __restrict__ coord,
                                                   const int* __restrict__ mask,
                                                   uint32_t* __restrict__ gwb,
                                                   uint32_t* __restrict__ fwb) {
    int wid  = blockIdx.x * 4 + (threadIdx.x >> 6);   // global q-row id = bt*512 + q
    int lane = threadIdx.x & 63;
    int q  = wid & 511;
    int bt = wid >> 9;
    const float* cb = coord + (size_t)bt * S_ * 3;
    const int* mrow = mask + (size_t)bt * S_;
    float cq0 = cb[q*3+0], cq1 = cb[q*3+1], cq2 = cb[q*3+2];
    for (int i = 0; i < 8; ++i) {
        int k = i * 64 + lane;
        float dx = cq0 - cb[k*3+0];
        float dy = cq1 - cb[k*3+1];
        float dz = cq2 - cb[k*3+2];
        bool near = (dx*dx + dy*dy + dz*dz) < 625.0f;
        bool um = (mrow[k] == 0);
        unsigned long long g = __ballot(near && um);
        unsigned long long f = __ballot((!near) && um);
        if (lane == 0) {
            gwb[(size_t)wid*16 + i*2]     = (uint32_t)g;
            gwb[(size_t)wid*16 + i*2 + 1] = (uint32_t)(g >> 32);
            fwb[(size_t)wid*16 + i*2]     = (uint32_t)f;
            fwb[(size_t)wid*16 + i*2 + 1] = (uint32_t)(f >> 32);
        }
    }
}

// ---------------- distance-gated attention (LDS-staged flash) ----------------
// grid = B*H*T*2 blocks, 256 threads; block handles 256 queries of one (b,h,t).
// K,V staged in LDS as fp16 [512][32]; inner loop reads are wave-uniform broadcasts.
__global__ __launch_bounds__(256) void attn_kernel(
        const float* __restrict__ q, const float* __restrict__ k,
        const float* __restrict__ v, const uint32_t* __restrict__ gwb,
        const uint32_t* __restrict__ fwb, float* __restrict__ out) {
    __shared__ _Float16 Ks[S_ * HD_];   // 32 KB
    __shared__ _Float16 Vs[S_ * HD_];   // 32 KB
    int bid  = blockIdx.x;
    int half = bid & 1;
    int bht  = bid >> 1;
    int t = bht & (T_-1), h = (bht >> 4) & (H_-1), b = bht >> 7;
    int tid = threadIdx.x;
    size_t headbase = (((size_t)b * C_ + h * HD_) * T_ + t) * S_;
    const float* kg = k + headbase;
    const float* vg = v + headbase;

    // stage K,V -> LDS (coalesced global reads; LDS write conflicts are negligible)
    for (int i = tid; i < S_ * HD_; i += 256) {
        int d = i >> 9, s = i & (S_-1);
        Ks[s * HD_ + d] = (_Float16)kg[(size_t)d * NTS + s];
        Vs[s * HD_ + d] = (_Float16)vg[(size_t)d * NTS + s];
    }

    int qi = half * 256 + tid;
    // load (pre-scaled) query into registers
    float qr[HD_];
    const float* qg = q + headbase;
    #pragma unroll
    for (int d = 0; d < HD_; ++d)
        qr[d] = qg[(size_t)d * NTS + qi] * 0.17677669529663687f;  // 1/sqrt(32)

    const uint32_t* gwp = gwb + ((size_t)(b * T_ + t) * S_ + qi) * 16;
    const uint32_t* fwp = fwb + ((size_t)(b * T_ + t) * S_ + qi) * 16;

    __syncthreads();

    float O[HD_] = {};
    float l = 0.f;
    for (int w = 0; w < 16; ++w) {
        uint32_t gword = gwp[w];
        uint32_t fword = fwp[w];
        #pragma unroll 4
        for (int j = 0; j < 32; ++j) {
            int kk = w * 32 + j;
            const half8* kr = (const half8*)(Ks + (size_t)kk * HD_);
            half8 k0 = kr[0], k1 = kr[1], k2 = kr[2], k3 = kr[3];
            float a0 = 0.f, a1 = 0.f, a2 = 0.f, a3 = 0.f;
            #pragma unroll
            for (int d = 0; d < 8; ++d) {
                a0 = fmaf((float)k0[d], qr[d],      a0);
                a1 = fmaf((float)k1[d], qr[d + 8],  a1);
                a2 = fmaf((float)k2[d], qr[d + 16], a2);
                a3 = fmaf((float)k3[d], qr[d + 24], a3);
            }
            float s = (a0 + a1) + (a2 + a3);
            uint32_t gb = (gword >> j) & 1u;
            uint32_t fb = (fword >> j) & 1u;
            float lg = gb ? fminf(s, 80.f) : 0.f;   // gated-off (far) -> logit 0
            float e  = __expf(lg);                  // exp(0)=1 covers far keys
            e = (gb | fb) ? e : 0.f;                // masked -> 0
            l += e;
            const half8* vr = (const half8*)(Vs + (size_t)kk * HD_);
            half8 v0 = vr[0], v1 = vr[1], v2 = vr[2], v3 = vr[3];
            #pragma unroll
            for (int d = 0; d < 8; ++d) {
                O[d]      = fmaf((float)v0[d], e, O[d]);
                O[d + 8]  = fmaf((float)v1[d], e, O[d + 8]);
                O[d + 16] = fmaf((float)v2[d], e, O[d + 16]);
                O[d + 24] = fmaf((float)v3[d], e, O[d + 24]);
            }
        }
    }
    float inv = 1.0f / l;
    #pragma unroll
    for (int d = 0; d < HD_; ++d)
        out[headbase + (size_t)d * NTS + qi] = O[d] * inv;
}

// ---------------- driver ----------------
extern "C" void kernel_launch(void* const* d_in, const int* in_sizes, int n_in,
                              void* d_out, int out_size, void* d_ws, size_t ws_size,
                              hipStream_t stream) {
    const float* decoder = (const float*)d_in[0];
    const float* encoder = (const float*)d_in[1];
    const float* pos     = (const float*)d_in[2];
    const float* coord   = (const float*)d_in[3];
    const int*   mask    = (const int*)d_in[4];
    const float* Wq = (const float*)d_in[5],  *bq = (const float*)d_in[6];
    const float* Wk = (const float*)d_in[7],  *bk = (const float*)d_in[8];
    const float* Wv = (const float*)d_in[9],  *bv = (const float*)d_in[10];
    const float* Wo = (const float*)d_in[11], *bo = (const float*)d_in[12];
    const float* W1 = (const float*)d_in[13], *b1 = (const float*)d_in[14];
    const float* W2 = (const float*)d_in[15], *b2 = (const float*)d_in[16];
    const float* ln_g = (const float*)d_in[17], *ln_b = (const float*)d_in[18];

    float* dec = (float*)d_out;
    float* ws  = (float*)d_ws;
    float* buf0 = ws;
    float* buf1 = ws + NELEM;
    float* buf2 = ws + 2*NELEM;
    float* buf3 = ws + 3*NELEM;
    float* hbuf = buf1;                 // spans buf1..buf4 (4*NELEM)
    uint32_t* gwb = (uint32_t*)(ws + 5*NELEM);                 // 1 MB
    uint32_t* fwb = gwb + (size_t)B_*T_*S_*16;                 // 1 MB

    int n4 = (int)(NELEM / 4);
    dim3 ewGrid(n4 / 256);
    dim3 gemmGridC(NTS/64, C_/64, B_);
    dim3 gemmGridF(NTS/64, DFF_/64, B_);
    dim3 lnGrid(B_ * T_ * (S_/256));
    dim3 attnGrid(B_ * H_ * T_ * 2);
    dim3 gateGrid(B_ * T_ * S_ / 4);

    copy_kernel<<<ewGrid, 256, 0, stream>>>(decoder, dec, n4);
    gate_kernel<<<gateGrid, 256, 0, stream>>>(coord, mask, gwb, fwb);

    for (int l = 0; l < L_; ++l) {
        const float* Wq_l = Wq + (size_t)l*C_*C_;  const float* bq_l = bq + l*C_;
        const float* Wk_l = Wk + (size_t)l*C_*C_;  const float* bk_l = bk + l*C_;
        const float* Wv_l = Wv + (size_t)l*C_*C_;  const float* bv_l = bv + l*C_;
        const float* Wo_l = Wo + (size_t)l*C_*C_;  const float* bo_l = bo + l*C_;
        const float* W1_l = W1 + (size_t)l*DFF_*C_; const float* b1_l = b1 + l*DFF_;
        const float* W2_l = W2 + (size_t)l*C_*DFF_; const float* b2_l = b2 + l*C_;
        const float* g0 = ln_g + ((size_t)l*3 + 0)*C_; const float* e0 = ln_b + ((size_t)l*3 + 0)*C_;
        const float* g1 = ln_g + ((size_t)l*3 + 1)*C_; const float* e1 = ln_b + ((size_t)l*3 + 1)*C_;
        const float* g2 = ln_g + ((size_t)l*3 + 2)*C_; const float* e2 = ln_b + ((size_t)l*3 + 2)*C_;

        // ---- block A: self-attention, qk = LN(dec)+pos, v-input = LN(dec)
        ln_kernel<<<lnGrid, 256, 0, stream>>>(dec, g0, e0, pos, buf0, buf1);
        gemm_cc<0><<<gemmGridC, 256, 0, stream>>>(Wq_l, bq_l, buf1, buf2, C_, C_);
        gemm_cc<0><<<gemmGridC, 256, 0, stream>>>(Wk_l, bk_l, buf1, buf3, C_, C_);
        gemm_cc<0><<<gemmGridC, 256, 0, stream>>>(Wv_l, bv_l, buf0, buf1, C_, C_);
        attn_kernel<<<attnGrid, 256, 0, stream>>>(buf2, buf3, buf1, gwb, fwb, buf0);
        gemm_cc<1><<<gemmGridC, 256, 0, stream>>>(Wo_l, bo_l, buf0, dec, C_, C_);

        // ---- block B: qk = encoder+pos, v-input = LN(dec)
        ln_kernel<<<lnGrid, 256, 0, stream>>>(dec, g1, e1, nullptr, buf0, nullptr);
        add_kernel<<<ewGrid, 256, 0, stream>>>(encoder, pos, buf1, n4);
        gemm_cc<0><<<gemmGridC, 256, 0, stream>>>(Wq_l, bq_l, buf1, buf2, C_, C_);
        gemm_cc<0><<<gemmGridC, 256, 0, stream>>>(Wk_l, bk_l, buf1, buf3, C_, C_);
        gemm_cc<0><<<gemmGridC, 256, 0, stream>>>(Wv_l, bv_l, buf0, buf1, C_, C_);
        attn_kernel<<<attnGrid, 256, 0, stream>>>(buf2, buf3, buf1, gwb, fwb, buf0);
        gemm_cc<1><<<gemmGridC, 256, 0, stream>>>(Wo_l, bo_l, buf0, dec, C_, C_);

        // ---- FFN
        ln_kernel<<<lnGrid, 256, 0, stream>>>(dec, g2, e2, nullptr, buf0, nullptr);
        gemm_cc<2><<<gemmGridF, 256, 0, stream>>>(W1_l, b1_l, buf0, hbuf, DFF_, C_);
        gemm_cc<1><<<gemmGridC, 256, 0, stream>>>(W2_l, b2_l, hbuf, dec, C_, DFF_);
    }
}

// Round 3
// 1042.522 us; speedup vs baseline: 6.2017x; 2.6550x over previous
//
#include <hip/hip_runtime.h>
#include <math.h>

#define L_ 2
#define B_ 2
#define C_ 256
#define H_ 8
#define HD_ 32
#define T_ 16
#define S_ 512
#define DFF_ 1024
#define NTS (T_*S_)                 // 8192
#define NELEM ((size_t)B_*C_*T_*S_) // 4194304

typedef _Float16 half8v __attribute__((ext_vector_type(8)));
typedef _Float16 half4v __attribute__((ext_vector_type(4)));
typedef float   float4v __attribute__((ext_vector_type(4)));

// ---------------- elementwise ----------------
__global__ void copy_kernel(const float* __restrict__ src, float* __restrict__ dst, int n4) {
    int i = blockIdx.x * blockDim.x + threadIdx.x;
    if (i < n4) ((float4*)dst)[i] = ((const float4*)src)[i];
}

__global__ void cvt_kernel(const float* __restrict__ s, _Float16* __restrict__ d, int n) {
    int i = blockIdx.x * blockDim.x + threadIdx.x;
    if (i < n) d[i] = (_Float16)s[i];
}

// ---------------- layernorm over C, write fp16 transposed [b][ts][c] ----------------
__global__ __launch_bounds__(64) void ln_t(const float* __restrict__ x,
                                           const float* __restrict__ gam,
                                           const float* __restrict__ bet,
                                           const float* __restrict__ pos,
                                           _Float16* __restrict__ s2,
                                           _Float16* __restrict__ qk) {
    int idx = blockIdx.x * 64 + threadIdx.x;   // b*8192 + n
    int b = idx >> 13, n = idx & 8191;
    const float* xb = x + (size_t)b * C_ * NTS + n;
    const float* pb = pos ? pos + (size_t)b * C_ * NTS + n : nullptr;
    float sum = 0.f, sq = 0.f;
    for (int c = 0; c < C_; ++c) {
        float v = xb[(size_t)c * NTS];
        sum += v; sq += v * v;
    }
    float mean = sum * (1.0f / C_);
    float var  = sq * (1.0f / C_) - mean * mean;
    float rstd = rsqrtf(var + 1e-5f);
    _Float16* s2r = s2 + (size_t)idx * C_;
    _Float16* qkr = qk ? qk + (size_t)idx * C_ : nullptr;
    for (int c0 = 0; c0 < C_; c0 += 8) {
        half8v hv, qv;
        #pragma unroll
        for (int j = 0; j < 8; ++j) {
            int c = c0 + j;
            float y = (xb[(size_t)c * NTS] - mean) * rstd * gam[c] + bet[c];
            hv[j] = (_Float16)y;
            if (qk) qv[j] = (_Float16)(y + pb[(size_t)c * NTS]);
        }
        *(half8v*)(s2r + c0) = hv;
        if (qk) *(half8v*)(qkr + c0) = qv;
    }
}

// enc+pos -> fp16 transposed [b][ts][c]
__global__ __launch_bounds__(64) void addt_kernel(const float* __restrict__ a,
                                                  const float* __restrict__ p,
                                                  _Float16* __restrict__ o) {
    int idx = blockIdx.x * 64 + threadIdx.x;
    int b = idx >> 13, n = idx & 8191;
    const float* ab = a + (size_t)b * C_ * NTS + n;
    const float* pb = p + (size_t)b * C_ * NTS + n;
    _Float16* orow = o + (size_t)idx * C_;
    for (int c0 = 0; c0 < C_; c0 += 8) {
        half8v hv;
        #pragma unroll
        for (int j = 0; j < 8; ++j) {
            int c = c0 + j;
            hv[j] = (_Float16)(ab[(size_t)c * NTS] + pb[(size_t)c * NTS]);
        }
        *(half8v*)(orow + c0) = hv;
    }
}

// ---------------- MFMA fp16 GEMM ----------------
// Y = W[M][K] * X^T  with X fp16 [b][N=8192][K] (K-major rows).
// MODE 0: Y fp16 [b][n][M] (store);  1: dec f32 [b][M][N] += (residual);
// MODE 2: relu, Y fp16 [b][n][M].
// Tiles 128x128, BK=32, 4 waves of 64x64, mfma_f32_16x16x32_f16.
template<int MODE>
__global__ __launch_bounds__(256) void gemm_mfma(const _Float16* __restrict__ W,
                                                 const float* __restrict__ bias,
                                                 const _Float16* __restrict__ X,
                                                 void* __restrict__ Yv, int M, int K) {
    __shared__ _Float16 As[128 * 32];
    __shared__ _Float16 Bs[128 * 32];
    int b  = blockIdx.z;
    int m0 = blockIdx.y * 128;
    int n0 = blockIdx.x * 128;
    const _Float16* Xb = X + (size_t)b * NTS * K;
    int tid = threadIdx.x;
    int wave = tid >> 6, lane = tid & 63;
    int wm = (wave >> 1) * 64, wn = (wave & 1) * 64;
    int r = lane & 15, g = lane >> 4;
    float4v acc[4][4];
    #pragma unroll
    for (int i = 0; i < 4; ++i)
        #pragma unroll
        for (int j = 0; j < 4; ++j) acc[i][j] = (float4v){0.f, 0.f, 0.f, 0.f};

    for (int k0 = 0; k0 < K; k0 += 32) {
        // stage A,B: 512 chunks of 16B each, XOR-swizzled chunk position
        #pragma unroll
        for (int it = 0; it < 2; ++it) {
            int c = tid + it * 256;
            int row = c >> 2, ch = c & 3;
            int sw = (ch ^ (row & 3)) << 3;
            *(half8v*)(As + row * 32 + sw) =
                *(const half8v*)(W + (size_t)(m0 + row) * K + k0 + ch * 8);
            *(half8v*)(Bs + row * 32 + sw) =
                *(const half8v*)(Xb + (size_t)(n0 + row) * K + k0 + ch * 8);
        }
        __syncthreads();
        half8v af[4], bf[4];
        #pragma unroll
        for (int mt = 0; mt < 4; ++mt) {
            int row = wm + mt * 16 + r;
            af[mt] = *(const half8v*)(As + row * 32 + ((g ^ (row & 3)) << 3));
        }
        #pragma unroll
        for (int nt = 0; nt < 4; ++nt) {
            int row = wn + nt * 16 + r;
            bf[nt] = *(const half8v*)(Bs + row * 32 + ((g ^ (row & 3)) << 3));
        }
        #pragma unroll
        for (int mt = 0; mt < 4; ++mt)
            #pragma unroll
            for (int nt = 0; nt < 4; ++nt)
                acc[mt][nt] = __builtin_amdgcn_mfma_f32_16x16x32_f16(af[mt], bf[nt], acc[mt][nt], 0, 0, 0);
        __syncthreads();
    }

    // epilogue: C/D layout col(n)=lane&15, row(m)=(lane>>4)*4+reg
    #pragma unroll
    for (int mt = 0; mt < 4; ++mt) {
        int m_base = m0 + wm + mt * 16 + g * 4;
        float bb[4];
        #pragma unroll
        for (int rr = 0; rr < 4; ++rr) bb[rr] = bias[m_base + rr];
        #pragma unroll
        for (int nt = 0; nt < 4; ++nt) {
            int n = n0 + wn + nt * 16 + r;
            if (MODE == 1) {
                float* Yd = (float*)Yv + (size_t)b * M * NTS;
                #pragma unroll
                for (int rr = 0; rr < 4; ++rr) {
                    size_t o = (size_t)(m_base + rr) * NTS + n;
                    Yd[o] += acc[mt][nt][rr] + bb[rr];
                }
            } else {
                _Float16* Y = (_Float16*)Yv + (size_t)b * NTS * M;
                half4v hv;
                #pragma unroll
                for (int rr = 0; rr < 4; ++rr) {
                    float v = acc[mt][nt][rr] + bb[rr];
                    if (MODE == 2) v = fmaxf(v, 0.f);
                    hv[rr] = (_Float16)v;
                }
                *(half4v*)(Y + (size_t)n * M + m_base) = hv;
            }
        }
    }
}

// ---------------- gate/mask bit precompute ----------------
__global__ __launch_bounds__(256) void gate_kernel(const float* __restrict__ coord,
                                                   const int* __restrict__ mask,
                                                   uint32_t* __restrict__ gwb,
                                                   uint32_t* __restrict__ fwb) {
    int wid  = blockIdx.x * 4 + (threadIdx.x >> 6);   // global q-row id = bt*512 + q
    int lane = threadIdx.x & 63;
    int q  = wid & 511;
    int bt = wid >> 9;
    const float* cb = coord + (size_t)bt * S_ * 3;
    const int* mrow = mask + (size_t)bt * S_;
    float cq0 = cb[q*3+0], cq1 = cb[q*3+1], cq2 = cb[q*3+2];
    for (int i = 0; i < 8; ++i) {
        int k = i * 64 + lane;
        float dx = cq0 - cb[k*3+0];
        float dy = cq1 - cb[k*3+1];
        float dz = cq2 - cb[k*3+2];
        bool near = (dx*dx + dy*dy + dz*dz) < 625.0f;
        bool um = (mrow[k] == 0);
        unsigned long long gmask = __ballot(near && um);
        unsigned long long fmask = __ballot((!near) && um);
        if (lane == 0) {
            gwb[(size_t)wid*16 + i*2]     = (uint32_t)gmask;
            gwb[(size_t)wid*16 + i*2 + 1] = (uint32_t)(gmask >> 32);
            fwb[(size_t)wid*16 + i*2]     = (uint32_t)fmask;
            fwb[(size_t)wid*16 + i*2 + 1] = (uint32_t)(fmask >> 32);
        }
    }
}

// ---------------- sparse distance-gated attention ----------------
// Exploits: far-unmasked keys contribute exp(0)=1 exactly.
// O_num = U + sum_near (e-1)*V ;  l = u + sum_near (e-1);  out = O_num / l
// where U = sum over unmasked V (query-independent), u = per-query unmasked count.
// q,k,v,out: fp16 [b][ts][256], head slice at c = h*32.
// grid = B*H*T*2, block 256; block covers 256 queries of one (b,h,t).
__global__ __launch_bounds__(256) void attn_kernel(
        const _Float16* __restrict__ q, const _Float16* __restrict__ k,
        const _Float16* __restrict__ v, const int* __restrict__ mask,
        const uint32_t* __restrict__ gwb, const uint32_t* __restrict__ fwb,
        _Float16* __restrict__ out) {
    __shared__ _Float16 Ks[S_ * HD_];   // 32 KB, rows [s][32]
    __shared__ _Float16 Vs[S_ * HD_];   // 32 KB
    __shared__ float Upart[8][HD_];
    __shared__ float Ufin[HD_];
    int bid  = blockIdx.x;
    int half = bid & 1;
    int bht  = bid >> 1;
    int t = bht & (T_-1), h = (bht >> 4) & (H_-1), b = bht >> 7;
    int tid = threadIdx.x;
    size_t rowbase = ((size_t)b * NTS + t * S_) * C_ + h * HD_;  // [b][t*512+s][h*32]

    // stage K,V verbatim (fp16, conflict-free b128 writes)
    for (int it = 0; it < 8; ++it) {
        int c = tid + it * 256;             // chunk id: s = c>>2, ch = c&3
        int s = c >> 2, ch = c & 3;
        *(half8v*)(Ks + s * HD_ + ch * 8) = *(const half8v*)(k + rowbase + (size_t)s * C_ + ch * 8);
        *(half8v*)(Vs + s * HD_ + ch * 8) = *(const half8v*)(v + rowbase + (size_t)s * C_ + ch * 8);
    }

    int qi = half * 256 + tid;
    // query into f32 regs, pre-scaled
    float qr[HD_];
    {
        const half8v* q8 = (const half8v*)(q + rowbase + (size_t)qi * C_);
        #pragma unroll
        for (int c0 = 0; c0 < 4; ++c0) {
            half8v hv = q8[c0];
            #pragma unroll
            for (int j = 0; j < 8; ++j)
                qr[c0*8+j] = (float)hv[j] * 0.17677669529663687f;
        }
    }
    __syncthreads();

    // U = sum over unmasked V  (partials over 8 key-groups)
    const int* mrow = mask + (size_t)(b * T_ + t) * S_;
    {
        int d = tid & 31, grp = tid >> 5;
        float s = 0.f;
        for (int kk = 0; kk < 64; ++kk) {
            int key = grp * 64 + kk;
            if (mrow[key] == 0) s += (float)Vs[key * HD_ + d];
        }
        Upart[grp][d] = s;
    }
    __syncthreads();
    if (tid < HD_) {
        float s = 0.f;
        #pragma unroll
        for (int gp = 0; gp < 8; ++gp) s += Upart[gp][tid];
        Ufin[tid] = s;
    }
    __syncthreads();

    // sparse near-key loop
    const uint32_t* gwp = gwb + ((size_t)(b * T_ + t) * S_ + qi) * 16;
    const uint32_t* fwp = fwb + ((size_t)(b * T_ + t) * S_ + qi) * 16;
    float O[HD_];
    #pragma unroll
    for (int d = 0; d < HD_; ++d) O[d] = 0.f;
    float l = 0.f;
    int ucnt = 0;
    for (int w = 0; w < 16; ++w) {
        uint32_t gw = gwp[w];
        ucnt += __builtin_popcount(gw) + __builtin_popcount(fwp[w]);
        while (gw) {
            int j = __builtin_ctz(gw);
            gw &= gw - 1;
            int key = w * 32 + j;
            const _Float16* kr = Ks + key * HD_;
            float s = 0.f;
            #pragma unroll
            for (int d = 0; d < HD_; ++d) s = fmaf((float)kr[d], qr[d], s);
            float e = __expf(fminf(s, 80.f));
            float em1 = e - 1.f;
            l += em1;
            const _Float16* vr = Vs + key * HD_;
            #pragma unroll
            for (int d = 0; d < HD_; ++d) O[d] = fmaf((float)vr[d], em1, O[d]);
        }
    }
    l += (float)ucnt;
    float invl = 1.0f / l;
    _Float16* orow = out + rowbase + (size_t)qi * C_;
    #pragma unroll
    for (int c0 = 0; c0 < 4; ++c0) {
        half8v hv;
        #pragma unroll
        for (int j = 0; j < 8; ++j)
            hv[j] = (_Float16)((O[c0*8+j] + Ufin[c0*8+j]) * invl);
        *(half8v*)(orow + c0 * 8) = hv;
    }
}

// ---------------- driver ----------------
extern "C" void kernel_launch(void* const* d_in, const int* in_sizes, int n_in,
                              void* d_out, int out_size, void* d_ws, size_t ws_size,
                              hipStream_t stream) {
    const float* decoder = (const float*)d_in[0];
    const float* encoder = (const float*)d_in[1];
    const float* pos     = (const float*)d_in[2];
    const float* coord   = (const float*)d_in[3];
    const int*   mask    = (const int*)d_in[4];
    const float* Wq = (const float*)d_in[5],  *bq = (const float*)d_in[6];
    const float* Wk = (const float*)d_in[7],  *bk = (const float*)d_in[8];
    const float* Wv = (const float*)d_in[9],  *bv = (const float*)d_in[10];
    const float* Wo = (const float*)d_in[11], *bo = (const float*)d_in[12];
    const float* W1 = (const float*)d_in[13], *b1 = (const float*)d_in[14];
    const float* W2 = (const float*)d_in[15], *b2 = (const float*)d_in[16];
    const float* ln_g = (const float*)d_in[17], *ln_b = (const float*)d_in[18];

    float* dec = (float*)d_out;

    // fp16 activation buffers [b][ts][c] + fp16 weights + gate bits
    size_t actsz = (size_t)B_ * NTS * C_;          // 4.19M halves
    _Float16* qkT = (_Float16*)d_ws;
    _Float16* qT  = qkT + actsz;
    _Float16* kT  = qT + actsz;
    _Float16* vT  = kT + actsz;
    _Float16* s2T = vT + actsz;                    // also reused as valsT
    _Float16* hT  = qkT;                           // FFN hidden: spans qkT..vT (32MB)
    _Float16* whq = s2T + actsz;
    _Float16* whk = whq + (size_t)L_*C_*C_;
    _Float16* whv = whk + (size_t)L_*C_*C_;
    _Float16* who = whv + (size_t)L_*C_*C_;
    _Float16* wh1 = who + (size_t)L_*C_*C_;
    _Float16* wh2 = wh1 + (size_t)L_*DFF_*C_;
    uint32_t* gwb = (uint32_t*)(wh2 + (size_t)L_*C_*DFF_);
    uint32_t* fwb = gwb + (size_t)B_*T_*S_*16;

    int n4 = (int)(NELEM / 4);
    dim3 ewGrid(n4 / 256);
    dim3 gGridC(NTS/128, C_/128, B_);     // (64, 2, 2)
    dim3 gGridF(NTS/128, DFF_/128, B_);   // (64, 8, 2)
    dim3 lnGrid(B_ * NTS / 64);           // 256 blocks x 64 thr
    dim3 attnGrid(B_ * H_ * T_ * 2);
    dim3 gateGrid(B_ * T_ * S_ / 4);

    copy_kernel<<<ewGrid, 256, 0, stream>>>(decoder, dec, n4);
    gate_kernel<<<gateGrid, 256, 0, stream>>>(coord, mask, gwb, fwb);
    int wn1 = L_*C_*C_, wn2 = L_*DFF_*C_;
    cvt_kernel<<<(wn1+255)/256, 256, 0, stream>>>(Wq, whq, wn1);
    cvt_kernel<<<(wn1+255)/256, 256, 0, stream>>>(Wk, whk, wn1);
    cvt_kernel<<<(wn1+255)/256, 256, 0, stream>>>(Wv, whv, wn1);
    cvt_kernel<<<(wn1+255)/256, 256, 0, stream>>>(Wo, who, wn1);
    cvt_kernel<<<(wn2+255)/256, 256, 0, stream>>>(W1, wh1, wn2);
    cvt_kernel<<<(wn2+255)/256, 256, 0, stream>>>(W2, wh2, wn2);

    for (int l = 0; l < L_; ++l) {
        const _Float16* whq_l = whq + (size_t)l*C_*C_;  const float* bq_l = bq + l*C_;
        const _Float16* whk_l = whk + (size_t)l*C_*C_;  const float* bk_l = bk + l*C_;
        const _Float16* whv_l = whv + (size_t)l*C_*C_;  const float* bv_l = bv + l*C_;
        const _Float16* who_l = who + (size_t)l*C_*C_;  const float* bo_l = bo + l*C_;
        const _Float16* wh1_l = wh1 + (size_t)l*DFF_*C_; const float* b1_l = b1 + l*DFF_;
        const _Float16* wh2_l = wh2 + (size_t)l*C_*DFF_; const float* b2_l = b2 + l*C_;
        const float* g0 = ln_g + ((size_t)l*3 + 0)*C_; const float* e0 = ln_b + ((size_t)l*3 + 0)*C_;
        const float* g1 = ln_g + ((size_t)l*3 + 1)*C_; const float* e1 = ln_b + ((size_t)l*3 + 1)*C_;
        const float* g2 = ln_g + ((size_t)l*3 + 2)*C_; const float* e2 = ln_b + ((size_t)l*3 + 2)*C_;

        // ---- block A: self-attention, qk = LN(dec)+pos, v-input = LN(dec)
        ln_t<<<lnGrid, 64, 0, stream>>>(dec, g0, e0, pos, s2T, qkT);
        gemm_mfma<0><<<gGridC, 256, 0, stream>>>(whq_l, bq_l, qkT, qT, C_, C_);
        gemm_mfma<0><<<gGridC, 256, 0, stream>>>(whk_l, bk_l, qkT, kT, C_, C_);
        gemm_mfma<0><<<gGridC, 256, 0, stream>>>(whv_l, bv_l, s2T, vT, C_, C_);
        attn_kernel<<<attnGrid, 256, 0, stream>>>(qT, kT, vT, mask, gwb, fwb, s2T);
        gemm_mfma<1><<<gGridC, 256, 0, stream>>>(who_l, bo_l, s2T, dec, C_, C_);

        // ---- block B: qk = encoder+pos, v-input = LN(dec)
        ln_t<<<lnGrid, 64, 0, stream>>>(dec, g1, e1, nullptr, s2T, nullptr);
        addt_kernel<<<lnGrid, 64, 0, stream>>>(encoder, pos, qkT);
        gemm_mfma<0><<<gGridC, 256, 0, stream>>>(whq_l, bq_l, qkT, qT, C_, C_);
        gemm_mfma<0><<<gGridC, 256, 0, stream>>>(whk_l, bk_l, qkT, kT, C_, C_);
        gemm_mfma<0><<<gGridC, 256, 0, stream>>>(whv_l, bv_l, s2T, vT, C_, C_);
        attn_kernel<<<attnGrid, 256, 0, stream>>>(qT, kT, vT, mask, gwb, fwb, s2T);
        gemm_mfma<1><<<gGridC, 256, 0, stream>>>(who_l, bo_l, s2T, dec, C_, C_);

        // ---- FFN
        ln_t<<<lnGrid, 64, 0, stream>>>(dec, g2, e2, nullptr, s2T, nullptr);
        gemm_mfma<2><<<gGridF, 256, 0, stream>>>(wh1_l, b1_l, s2T, hT, DFF_, C_);
        gemm_mfma<1><<<gGridC, 256, 0, stream>>>(wh2_l, b2_l, hT, dec, C_, DFF_);
    }
}

// Round 4
// 664.972 us; speedup vs baseline: 9.7229x; 1.5678x over previous
//
#include <hip/hip_runtime.h>
#include <math.h>

#define L_ 2
#define B_ 2
#define C_ 256
#define H_ 8
#define HD_ 32
#define T_ 16
#define S_ 512
#define DFF_ 1024
#define NTS (T_*S_)                 // 8192
#define NELEM ((size_t)B_*C_*T_*S_) // 4194304

typedef _Float16 half8v __attribute__((ext_vector_type(8)));
typedef _Float16 half4v __attribute__((ext_vector_type(4)));
typedef float   float4v __attribute__((ext_vector_type(4)));

// ---------------- elementwise ----------------
__global__ void copy_kernel(const float* __restrict__ src, float* __restrict__ dst, int n4) {
    int i = blockIdx.x * blockDim.x + threadIdx.x;
    if (i < n4) ((float4*)dst)[i] = ((const float4*)src)[i];
}

__global__ void cvt_kernel(const float* __restrict__ s, _Float16* __restrict__ d, int n) {
    int i = blockIdx.x * blockDim.x + threadIdx.x;
    if (i < n) d[i] = (_Float16)s[i];
}

// ---------------- layernorm over C -> fp16 [b][ts][c] ----------------
// Block = 256 thr covers 32 positions. nl=tid&31 (position), cg=tid>>5 (8 channel
// groups of 32). Values held in registers (unrolled => 32 loads in flight);
// LDS reduce for mean/rstd; LDS tile transpose (XOR-swizzled 16B chunks) for
// coalesced [n][c] output.
template<bool HASPOS>
__global__ __launch_bounds__(256) void ln_t(const float* __restrict__ x,
                                            const float* __restrict__ gam,
                                            const float* __restrict__ bet,
                                            const float* __restrict__ pos,
                                            _Float16* __restrict__ s2,
                                            _Float16* __restrict__ qk) {
    __shared__ float redS[8][32];
    __shared__ float redQ[8][32];
    __shared__ _Float16 tiles[(HASPOS ? 2 : 1) * 32 * 256];
    _Float16* t0 = tiles;
    _Float16* t1 = tiles + 32 * 256;   // valid only when HASPOS
    int tid = threadIdx.x;
    int nl = tid & 31, cg = tid >> 5;
    int gpos = blockIdx.x * 32;        // global position index base (b*8192+n)
    int b = gpos >> 13, nb = gpos & 8191;
    const float* xb = x + (size_t)b * C_ * NTS + nb + nl;
    float xv[32], pv[HASPOS ? 32 : 1];
    float sum = 0.f, sq = 0.f;
    #pragma unroll
    for (int j = 0; j < 32; ++j) {
        float v = xb[(size_t)(cg * 32 + j) * NTS];
        xv[j] = v; sum += v; sq += v * v;
    }
    if (HASPOS) {
        const float* pb = pos + (size_t)b * C_ * NTS + nb + nl;
        #pragma unroll
        for (int j = 0; j < 32; ++j) pv[j] = pb[(size_t)(cg * 32 + j) * NTS];
    }
    redS[cg][nl] = sum; redQ[cg][nl] = sq;
    __syncthreads();
    float s = 0.f, q = 0.f;
    #pragma unroll
    for (int g = 0; g < 8; ++g) { s += redS[g][nl]; q += redQ[g][nl]; }
    float mean = s * (1.0f / C_);
    float var  = q * (1.0f / C_) - mean * mean;
    float rstd = rsqrtf(var + 1e-5f);
    #pragma unroll
    for (int jj = 0; jj < 4; ++jj) {
        half8v h0, h1;
        #pragma unroll
        for (int j2 = 0; j2 < 8; ++j2) {
            int j = jj * 8 + j2;
            int c = cg * 32 + j;
            float y = (xv[j] - mean) * rstd * gam[c] + bet[c];
            h0[j2] = (_Float16)y;
            if (HASPOS) h1[j2] = (_Float16)(y + pv[j]);
        }
        int cs = (cg * 4 + jj) ^ nl;    // swizzle 16B-chunk position within row
        *(half8v*)(t0 + nl * 256 + cs * 8) = h0;
        if (HASPOS) *(half8v*)(t1 + nl * 256 + cs * 8) = h1;
    }
    __syncthreads();
    #pragma unroll
    for (int it = 0; it < 4; ++it) {
        int chunk = tid + it * 256;
        int row = chunk >> 5, ch = chunk & 31;
        int cs = ch ^ row;
        half8v v0 = *(half8v*)(t0 + row * 256 + cs * 8);
        *(half8v*)(s2 + (size_t)(gpos + row) * C_ + ch * 8) = v0;
        if (HASPOS) {
            half8v v1 = *(half8v*)(t1 + row * 256 + cs * 8);
            *(half8v*)(qk + (size_t)(gpos + row) * C_ + ch * 8) = v1;
        }
    }
}

// enc+pos -> fp16 transposed [b][ts][c]; same tiling as ln_t
__global__ __launch_bounds__(256) void addt_kernel(const float* __restrict__ a,
                                                   const float* __restrict__ p,
                                                   _Float16* __restrict__ o) {
    __shared__ _Float16 t0[32 * 256];
    int tid = threadIdx.x;
    int nl = tid & 31, cg = tid >> 5;
    int gpos = blockIdx.x * 32;
    int b = gpos >> 13, nb = gpos & 8191;
    const float* ab = a + (size_t)b * C_ * NTS + nb + nl;
    const float* pb = p + (size_t)b * C_ * NTS + nb + nl;
    float av[32], pv[32];
    #pragma unroll
    for (int j = 0; j < 32; ++j) av[j] = ab[(size_t)(cg * 32 + j) * NTS];
    #pragma unroll
    for (int j = 0; j < 32; ++j) pv[j] = pb[(size_t)(cg * 32 + j) * NTS];
    #pragma unroll
    for (int jj = 0; jj < 4; ++jj) {
        half8v h0;
        #pragma unroll
        for (int j2 = 0; j2 < 8; ++j2) {
            int j = jj * 8 + j2;
            h0[j2] = (_Float16)(av[j] + pv[j]);
        }
        int cs = (cg * 4 + jj) ^ nl;
        *(half8v*)(t0 + nl * 256 + cs * 8) = h0;
    }
    __syncthreads();
    #pragma unroll
    for (int it = 0; it < 4; ++it) {
        int chunk = tid + it * 256;
        int row = chunk >> 5, ch = chunk & 31;
        half8v v0 = *(half8v*)(t0 + row * 256 + (ch ^ row) * 8);
        *(half8v*)(o + (size_t)(gpos + row) * C_ + ch * 8) = v0;
    }
}

// ---------------- MFMA fp16 GEMM ----------------
// Y = W[M][K] * X^T  with X fp16 [b][N=8192][K] (K-major rows).
// MODE 0: Y fp16 [b][n][M] (store);  1: dec f32 [b][M][N] += (residual);
// MODE 2: relu, Y fp16 [b][n][M].
// Tiles 128x128, BK=32, 4 waves of 64x64, mfma_f32_16x16x32_f16.
template<int MODE>
__global__ __launch_bounds__(256) void gemm_mfma(const _Float16* __restrict__ W,
                                                 const float* __restrict__ bias,
                                                 const _Float16* __restrict__ X,
                                                 void* __restrict__ Yv, int M, int K) {
    __shared__ _Float16 As[128 * 32];
    __shared__ _Float16 Bs[128 * 32];
    int b  = blockIdx.z;
    int m0 = blockIdx.y * 128;
    int n0 = blockIdx.x * 128;
    const _Float16* Xb = X + (size_t)b * NTS * K;
    int tid = threadIdx.x;
    int wave = tid >> 6, lane = tid & 63;
    int wm = (wave >> 1) * 64, wn = (wave & 1) * 64;
    int r = lane & 15, g = lane >> 4;
    float4v acc[4][4];
    #pragma unroll
    for (int i = 0; i < 4; ++i)
        #pragma unroll
        for (int j = 0; j < 4; ++j) acc[i][j] = (float4v){0.f, 0.f, 0.f, 0.f};

    for (int k0 = 0; k0 < K; k0 += 32) {
        #pragma unroll
        for (int it = 0; it < 2; ++it) {
            int c = tid + it * 256;
            int row = c >> 2, ch = c & 3;
            int sw = (ch ^ (row & 3)) << 3;
            *(half8v*)(As + row * 32 + sw) =
                *(const half8v*)(W + (size_t)(m0 + row) * K + k0 + ch * 8);
            *(half8v*)(Bs + row * 32 + sw) =
                *(const half8v*)(Xb + (size_t)(n0 + row) * K + k0 + ch * 8);
        }
        __syncthreads();
        half8v af[4], bf[4];
        #pragma unroll
        for (int mt = 0; mt < 4; ++mt) {
            int row = wm + mt * 16 + r;
            af[mt] = *(const half8v*)(As + row * 32 + ((g ^ (row & 3)) << 3));
        }
        #pragma unroll
        for (int nt = 0; nt < 4; ++nt) {
            int row = wn + nt * 16 + r;
            bf[nt] = *(const half8v*)(Bs + row * 32 + ((g ^ (row & 3)) << 3));
        }
        #pragma unroll
        for (int mt = 0; mt < 4; ++mt)
            #pragma unroll
            for (int nt = 0; nt < 4; ++nt)
                acc[mt][nt] = __builtin_amdgcn_mfma_f32_16x16x32_f16(af[mt], bf[nt], acc[mt][nt], 0, 0, 0);
        __syncthreads();
    }

    // epilogue: C/D layout col(n)=lane&15, row(m)=(lane>>4)*4+reg
    #pragma unroll
    for (int mt = 0; mt < 4; ++mt) {
        int m_base = m0 + wm + mt * 16 + g * 4;
        float bb[4];
        #pragma unroll
        for (int rr = 0; rr < 4; ++rr) bb[rr] = bias[m_base + rr];
        #pragma unroll
        for (int nt = 0; nt < 4; ++nt) {
            int n = n0 + wn + nt * 16 + r;
            if (MODE == 1) {
                float* Yd = (float*)Yv + (size_t)b * M * NTS;
                #pragma unroll
                for (int rr = 0; rr < 4; ++rr) {
                    size_t o = (size_t)(m_base + rr) * NTS + n;
                    Yd[o] += acc[mt][nt][rr] + bb[rr];
                }
            } else {
                _Float16* Y = (_Float16*)Yv + (size_t)b * NTS * M;
                half4v hv;
                #pragma unroll
                for (int rr = 0; rr < 4; ++rr) {
                    float v = acc[mt][nt][rr] + bb[rr];
                    if (MODE == 2) v = fmaxf(v, 0.f);
                    hv[rr] = (_Float16)v;
                }
                *(half4v*)(Y + (size_t)n * M + m_base) = hv;
            }
        }
    }
}

// ---------------- gate/mask bit precompute ----------------
__global__ __launch_bounds__(256) void gate_kernel(const float* __restrict__ coord,
                                                   const int* __restrict__ mask,
                                                   uint32_t* __restrict__ gwb,
                                                   uint32_t* __restrict__ fwb) {
    int wid  = blockIdx.x * 4 + (threadIdx.x >> 6);   // global q-row id = bt*512 + q
    int lane = threadIdx.x & 63;
    int q  = wid & 511;
    int bt = wid >> 9;
    const float* cb = coord + (size_t)bt * S_ * 3;
    const int* mrow = mask + (size_t)bt * S_;
    float cq0 = cb[q*3+0], cq1 = cb[q*3+1], cq2 = cb[q*3+2];
    for (int i = 0; i < 8; ++i) {
        int k = i * 64 + lane;
        float dx = cq0 - cb[k*3+0];
        float dy = cq1 - cb[k*3+1];
        float dz = cq2 - cb[k*3+2];
        bool near = (dx*dx + dy*dy + dz*dz) < 625.0f;
        bool um = (mrow[k] == 0);
        unsigned long long gmask = __ballot(near && um);
        unsigned long long fmask = __ballot((!near) && um);
        if (lane == 0) {
            gwb[(size_t)wid*16 + i*2]     = (uint32_t)gmask;
            gwb[(size_t)wid*16 + i*2 + 1] = (uint32_t)(gmask >> 32);
            fwb[(size_t)wid*16 + i*2]     = (uint32_t)fmask;
            fwb[(size_t)wid*16 + i*2 + 1] = (uint32_t)(fmask >> 32);
        }
    }
}

// ---------------- sparse distance-gated attention ----------------
// far-unmasked keys contribute exp(0)=1 exactly:
// O_num = U + sum_near (e-1)*V ;  l = u + sum_near (e-1);  out = O_num / l
__global__ __launch_bounds__(256) void attn_kernel(
        const _Float16* __restrict__ q, const _Float16* __restrict__ k,
        const _Float16* __restrict__ v, const int* __restrict__ mask,
        const uint32_t* __restrict__ gwb, const uint32_t* __restrict__ fwb,
        _Float16* __restrict__ out) {
    __shared__ _Float16 Ks[S_ * HD_];   // 32 KB, rows [s][32]
    __shared__ _Float16 Vs[S_ * HD_];   // 32 KB
    __shared__ float Upart[8][HD_];
    __shared__ float Ufin[HD_];
    int bid  = blockIdx.x;
    int half = bid & 1;
    int bht  = bid >> 1;
    int t = bht & (T_-1), h = (bht >> 4) & (H_-1), b = bht >> 7;
    int tid = threadIdx.x;
    size_t rowbase = ((size_t)b * NTS + t * S_) * C_ + h * HD_;  // [b][t*512+s][h*32]

    for (int it = 0; it < 8; ++it) {
        int c = tid + it * 256;
        int s = c >> 2, ch = c & 3;
        *(half8v*)(Ks + s * HD_ + ch * 8) = *(const half8v*)(k + rowbase + (size_t)s * C_ + ch * 8);
        *(half8v*)(Vs + s * HD_ + ch * 8) = *(const half8v*)(v + rowbase + (size_t)s * C_ + ch * 8);
    }

    int qi = half * 256 + tid;
    float qr[HD_];
    {
        const half8v* q8 = (const half8v*)(q + rowbase + (size_t)qi * C_);
        #pragma unroll
        for (int c0 = 0; c0 < 4; ++c0) {
            half8v hv = q8[c0];
            #pragma unroll
            for (int j = 0; j < 8; ++j)
                qr[c0*8+j] = (float)hv[j] * 0.17677669529663687f;
        }
    }
    __syncthreads();

    const int* mrow = mask + (size_t)(b * T_ + t) * S_;
    {
        int d = tid & 31, grp = tid >> 5;
        float s = 0.f;
        for (int kk = 0; kk < 64; ++kk) {
            int key = grp * 64 + kk;
            if (mrow[key] == 0) s += (float)Vs[key * HD_ + d];
        }
        Upart[grp][d] = s;
    }
    __syncthreads();
    if (tid < HD_) {
        float s = 0.f;
        #pragma unroll
        for (int gp = 0; gp < 8; ++gp) s += Upart[gp][tid];
        Ufin[tid] = s;
    }
    __syncthreads();

    const uint32_t* gwp = gwb + ((size_t)(b * T_ + t) * S_ + qi) * 16;
    const uint32_t* fwp = fwb + ((size_t)(b * T_ + t) * S_ + qi) * 16;
    float O[HD_];
    #pragma unroll
    for (int d = 0; d < HD_; ++d) O[d] = 0.f;
    float l = 0.f;
    int ucnt = 0;
    for (int w = 0; w < 16; ++w) {
        uint32_t gw = gwp[w];
        ucnt += __builtin_popcount(gw) + __builtin_popcount(fwp[w]);
        while (gw) {
            int j = __builtin_ctz(gw);
            gw &= gw - 1;
            int key = w * 32 + j;
            const _Float16* kr = Ks + key * HD_;
            float s = 0.f;
            #pragma unroll
            for (int d = 0; d < HD_; ++d) s = fmaf((float)kr[d], qr[d], s);
            float e = __expf(fminf(s, 80.f));
            float em1 = e - 1.f;
            l += em1;
            const _Float16* vr = Vs + key * HD_;
            #pragma unroll
            for (int d = 0; d < HD_; ++d) O[d] = fmaf((float)vr[d], em1, O[d]);
        }
    }
    l += (float)ucnt;
    float invl = 1.0f / l;
    _Float16* orow = out + rowbase + (size_t)qi * C_;
    #pragma unroll
    for (int c0 = 0; c0 < 4; ++c0) {
        half8v hv;
        #pragma unroll
        for (int j = 0; j < 8; ++j)
            hv[j] = (_Float16)((O[c0*8+j] + Ufin[c0*8+j]) * invl);
        *(half8v*)(orow + c0 * 8) = hv;
    }
}

// ---------------- driver ----------------
extern "C" void kernel_launch(void* const* d_in, const int* in_sizes, int n_in,
                              void* d_out, int out_size, void* d_ws, size_t ws_size,
                              hipStream_t stream) {
    const float* decoder = (const float*)d_in[0];
    const float* encoder = (const float*)d_in[1];
    const float* pos     = (const float*)d_in[2];
    const float* coord   = (const float*)d_in[3];
    const int*   mask    = (const int*)d_in[4];
    const float* Wq = (const float*)d_in[5],  *bq = (const float*)d_in[6];
    const float* Wk = (const float*)d_in[7],  *bk = (const float*)d_in[8];
    const float* Wv = (const float*)d_in[9],  *bv = (const float*)d_in[10];
    const float* Wo = (const float*)d_in[11], *bo = (const float*)d_in[12];
    const float* W1 = (const float*)d_in[13], *b1 = (const float*)d_in[14];
    const float* W2 = (const float*)d_in[15], *b2 = (const float*)d_in[16];
    const float* ln_g = (const float*)d_in[17], *ln_b = (const float*)d_in[18];

    float* dec = (float*)d_out;

    size_t actsz = (size_t)B_ * NTS * C_;
    _Float16* qkT = (_Float16*)d_ws;
    _Float16* qT  = qkT + actsz;
    _Float16* kT  = qT + actsz;
    _Float16* vT  = kT + actsz;
    _Float16* s2T = vT + actsz;
    _Float16* hT  = qkT;                           // FFN hidden spans qkT..vT
    _Float16* whq = s2T + actsz;
    _Float16* whk = whq + (size_t)L_*C_*C_;
    _Float16* whv = whk + (size_t)L_*C_*C_;
    _Float16* who = whv + (size_t)L_*C_*C_;
    _Float16* wh1 = who + (size_t)L_*C_*C_;
    _Float16* wh2 = wh1 + (size_t)L_*DFF_*C_;
    uint32_t* gwb = (uint32_t*)(wh2 + (size_t)L_*C_*DFF_);
    uint32_t* fwb = gwb + (size_t)B_*T_*S_*16;

    int n4 = (int)(NELEM / 4);
    dim3 ewGrid(n4 / 256);
    dim3 gGridC(NTS/128, C_/128, B_);     // (64, 2, 2)
    dim3 gGridF(NTS/128, DFF_/128, B_);   // (64, 8, 2)
    dim3 lnGrid(B_ * NTS / 32);           // 1024 blocks x 256 thr
    dim3 attnGrid(B_ * H_ * T_ * 2);
    dim3 gateGrid(B_ * T_ * S_ / 4);

    copy_kernel<<<ewGrid, 256, 0, stream>>>(decoder, dec, n4);
    gate_kernel<<<gateGrid, 256, 0, stream>>>(coord, mask, gwb, fwb);
    int wn1 = L_*C_*C_, wn2 = L_*DFF_*C_;
    cvt_kernel<<<(wn1+255)/256, 256, 0, stream>>>(Wq, whq, wn1);
    cvt_kernel<<<(wn1+255)/256, 256, 0, stream>>>(Wk, whk, wn1);
    cvt_kernel<<<(wn1+255)/256, 256, 0, stream>>>(Wv, whv, wn1);
    cvt_kernel<<<(wn1+255)/256, 256, 0, stream>>>(Wo, who, wn1);
    cvt_kernel<<<(wn2+255)/256, 256, 0, stream>>>(W1, wh1, wn2);
    cvt_kernel<<<(wn2+255)/256, 256, 0, stream>>>(W2, wh2, wn2);

    for (int l = 0; l < L_; ++l) {
        const _Float16* whq_l = whq + (size_t)l*C_*C_;  const float* bq_l = bq + l*C_;
        const _Float16* whk_l = whk + (size_t)l*C_*C_;  const float* bk_l = bk + l*C_;
        const _Float16* whv_l = whv + (size_t)l*C_*C_;  const float* bv_l = bv + l*C_;
        const _Float16* who_l = who + (size_t)l*C_*C_;  const float* bo_l = bo + l*C_;
        const _Float16* wh1_l = wh1 + (size_t)l*DFF_*C_; const float* b1_l = b1 + l*DFF_;
        const _Float16* wh2_l = wh2 + (size_t)l*C_*DFF_; const float* b2_l = b2 + l*C_;
        const float* g0 = ln_g + ((size_t)l*3 + 0)*C_; const float* e0 = ln_b + ((size_t)l*3 + 0)*C_;
        const float* g1 = ln_g + ((size_t)l*3 + 1)*C_; const float* e1 = ln_b + ((size_t)l*3 + 1)*C_;
        const float* g2 = ln_g + ((size_t)l*3 + 2)*C_; const float* e2 = ln_b + ((size_t)l*3 + 2)*C_;

        // ---- block A: self-attention, qk = LN(dec)+pos, v-input = LN(dec)
        ln_t<true><<<lnGrid, 256, 0, stream>>>(dec, g0, e0, pos, s2T, qkT);
        gemm_mfma<0><<<gGridC, 256, 0, stream>>>(whq_l, bq_l, qkT, qT, C_, C_);
        gemm_mfma<0><<<gGridC, 256, 0, stream>>>(whk_l, bk_l, qkT, kT, C_, C_);
        gemm_mfma<0><<<gGridC, 256, 0, stream>>>(whv_l, bv_l, s2T, vT, C_, C_);
        attn_kernel<<<attnGrid, 256, 0, stream>>>(qT, kT, vT, mask, gwb, fwb, s2T);
        gemm_mfma<1><<<gGridC, 256, 0, stream>>>(who_l, bo_l, s2T, dec, C_, C_);

        // ---- block B: qk = encoder+pos, v-input = LN(dec)
        ln_t<false><<<lnGrid, 256, 0, stream>>>(dec, g1, e1, nullptr, s2T, nullptr);
        addt_kernel<<<lnGrid, 256, 0, stream>>>(encoder, pos, qkT);
        gemm_mfma<0><<<gGridC, 256, 0, stream>>>(whq_l, bq_l, qkT, qT, C_, C_);
        gemm_mfma<0><<<gGridC, 256, 0, stream>>>(whk_l, bk_l, qkT, kT, C_, C_);
        gemm_mfma<0><<<gGridC, 256, 0, stream>>>(whv_l, bv_l, s2T, vT, C_, C_);
        attn_kernel<<<attnGrid, 256, 0, stream>>>(qT, kT, vT, mask, gwb, fwb, s2T);
        gemm_mfma<1><<<gGridC, 256, 0, stream>>>(who_l, bo_l, s2T, dec, C_, C_);

        // ---- FFN
        ln_t<false><<<lnGrid, 256, 0, stream>>>(dec, g2, e2, nullptr, s2T, nullptr);
        gemm_mfma<2><<<gGridF, 256, 0, stream>>>(wh1_l, b1_l, s2T, hT, DFF_, C_);
        gemm_mfma<1><<<gGridC, 256, 0, stream>>>(wh2_l, b2_l, hT, dec, C_, DFF_);
    }
}